// Round 15
// baseline (38.363 us; speedup 1.0000x reference)
//
#include <hip/hip_runtime.h>

#define NB 16
#define HH 1024
#define WW 1024
#define BW 128         // block width: 2 waves x 64 cols
#define BH 64          // block strip height (4 sub-tiles of 16)
#define WVT 4          // sub-tiles per wave strip
#define STH 16         // sub-tile height (output rows)
#define SLR 20         // staged rows per sub-tile (16 + 4 halo)
#define SLC 72         // staged cols (64 + 8 halo)
#define SQ4 (SLC / 4)  // 18 float4 per staged row
#define NEL (SLR * SQ4) // 360 float4 per sub-tile
#define NLD 6          // ceil(360/64) reg-loads per lane

#define EPS1 2e-4f     // edge-threshold confidence margin (f32 err bound ~3e-6)
#define EPS2 1e-4f     // final-threshold confidence margin (f32 err bound ~2e-5)

typedef float f32x4 __attribute__((ext_vector_type(4)));
typedef float f32x2 __attribute__((ext_vector_type(2)));

// Cold exact-path: recompute one pixel in f64 from the wave's LDS region
// (identical math to the R1 kernel that scored absmax 0.0 vs np/f64 ref).
__device__ __noinline__ float aes_exact(const float (*raw)[SLC], int lr, int lc,
                                        float bsf, float esf, float fthr)
{
    const double bfd   = (double)bsf / 3.0;
    const double ethrd = 0.5 * (double)esf;
    const double fthrd = (double)fthr;
    const double w25d  = (double)(1.0f / 25.0f);

    double s25 = 0.0, s9 = 0.0;
    for (int dy = 0; dy < 5; ++dy)
        for (int dx = 0; dx < 5; ++dx) {
            double v = (double)raw[lr + dy][lc + dx];
            s25 += v;
            if (dy >= 1 && dy <= 3 && dx >= 1 && dx <= 3) s9 += v;
        }
    double c      = (double)raw[lr + 2][lc + 2];
    double edges  = fabs(9.0 * c - s9);
    double sbase  = s25 * w25d;
    double smooth = c * (1.0 - bfd) + sbase * bfd;
    double result = (edges > ethrd) ? smooth : c;
    return (result > fthrd) ? 1.0f : 0.0f;
}

__global__ __launch_bounds__(128)
void aes_kernel(const float* __restrict__ mask,
                const float* __restrict__ blur_strength,
                const float* __restrict__ edge_sensitivity,
                const float* __restrict__ final_threshold,
                float* __restrict__ out)
{
    // wave-private staging regions -- NO __syncthreads anywhere in this kernel
    __shared__ float region[2][SLR][SLC];   // 11,520 B -> ~14 blocks/CU cap

    const int b       = blockIdx.z;
    const int strip_y = blockIdx.y * BH;
    const float* m = mask + (size_t)b * (HH * WW);

    const float bsf    = blur_strength[b];
    const float esf    = edge_sensitivity[b];
    const float fthr   = final_threshold[b];
    const float ethr   = 0.5f * esf;          // exact in f32
    const float bff    = bsf / 3.0f;
    const float onembf = 1.0f - bff;
    const float w25f   = 1.0f / 25.0f;

    const int lane = threadIdx.x & 63;
    const int wv   = threadIdx.x >> 6;            // 0 or 1
    const int wxb  = blockIdx.x * BW + wv * 64;   // wave's first output col

    // lane -> 4 cols x 4 rows micro-tile inside the 64x16 sub-tile
    const int cg  = lane & 15;        // col group
    const int rg  = lane >> 4;        // row group
    const int lr0 = rg * 4;           // region row of first window row
    const int lc0 = 4 * cg + 2;       // region col of (x0-2)

    float (*reg_)[SLC] = region[wv];
    f32x4 stg[NLD];    // in-flight staging registers (static index via unroll)

    // ---- issue 6 masked global loads for sub-tile T (no LDS, no waits) ----
#define LOADREGS(T)                                                         \
    {                                                                       \
        const int gy0 = strip_y + (T) * STH - 2;                            \
        _Pragma("unroll")                                                   \
        for (int k = 0; k < NLD; ++k) {                                     \
            int i = lane + k * 64;                                          \
            f32x4 v = {0.f, 0.f, 0.f, 0.f};                                 \
            if (i < NEL) {                                                  \
                int row = i / SQ4, q = i - row * SQ4;                       \
                int gy = gy0 + row;                                         \
                int gx = wxb - 4 + 4 * q;       /* 16B aligned */           \
                if ((unsigned)gy < (unsigned)HH && (unsigned)gx < (unsigned)WW) \
                    v = *(const f32x4*)(m + (size_t)gy * WW + gx);          \
            }                                                               \
            stg[k] = v;                                                     \
        }                                                                   \
    }

    // ---- write stg[] into the wave's region (compiler inserts vmcnt) ----
#define WRITELDS()                                                          \
    {                                                                       \
        _Pragma("unroll")                                                   \
        for (int k = 0; k < NLD; ++k) {                                     \
            int i = lane + k * 64;                                          \
            if (i < NEL) {                                                  \
                int row = i / SQ4, q = i - row * SQ4;                       \
                *(f32x4*)&reg_[row][4 * q] = stg[k];                        \
            }                                                               \
        }                                                                   \
    }

    // vectorized row load: h3 = (B+D)+C, h5 = (A+E)+h3 (R14's proven math)
#define LOADROWV(ROWIDX, K)                                                 \
    {                                                                       \
        const float* rp = &reg_[(ROWIDX)][0];                               \
        f32x2 u0 = *(const f32x2*)(rp + lc0);          /* a0 a1 */          \
        f32x4 u1 = *(const f32x4*)(rp + lc0 + 2);      /* a2..a5 */         \
        f32x2 u2 = *(const f32x2*)(rp + lc0 + 6);      /* a6 a7 */          \
        f32x4 A = {u0.x, u0.y, u1.x, u1.y};                                 \
        f32x4 B = {u0.y, u1.x, u1.y, u1.z};                                 \
        f32x4 D = {u1.y, u1.z, u1.w, u2.x};                                 \
        f32x4 E = {u1.z, u1.w, u2.x, u2.y};                                 \
        f32x4 h3v = (B + D) + u1;                                           \
        h3r[(K)] = h3v;                                                     \
        h5r[(K)] = (A + E) + h3v;                                           \
        ccr[(K)] = u1;                                                      \
    }

    // ---- compute sub-tile T from the wave's region (R14's body) ----
#define COMPUTE(T)                                                          \
    {                                                                       \
        f32x4 h5r[5], h3r[5], ccr[5];                                       \
        _Pragma("unroll")                                                   \
        for (int k = 0; k < 4; ++k)                                         \
            LOADROWV(lr0 + k, k)                                            \
        f32x4 S25 = (h5r[0] + h5r[1]) + (h5r[2] + h5r[3]);                  \
        float* op = out + (size_t)b * (HH * WW)                             \
                  + (size_t)(strip_y + (T) * STH + lr0) * WW + wxb + 4 * cg;\
        _Pragma("unroll")                                                   \
        for (int r = 0; r < 4; ++r) {                                       \
            LOADROWV(lr0 + r + 4, (r + 4) % 5)                              \
            const int i1 = (r + 1) % 5, i2 = (r + 2) % 5, i3 = (r + 3) % 5; \
            const int i4 = (r + 4) % 5;                                     \
            f32x4 S25f = S25 + h5r[i4];                                     \
            f32x4 S9   = (h3r[i1] + h3r[i3]) + h3r[i2];                     \
            f32x4 cc   = ccr[i2];                                           \
            f32x4 e    = cc * 9.0f - S9;                                    \
            f32x4 sb   = S25f * w25f;                                       \
            f32x4 sm   = cc * onembf + sb * bff;                            \
            f32x4 d2   = sm - fthr;                                         \
            f32x4 ov;                                                       \
            _Pragma("unroll")                                               \
            for (int c = 0; c < 4; ++c) {                                   \
                float ec  = fabsf(e[c]);                                    \
                float dd1 = ec - ethr;                                      \
                bool isedge = dd1 > 0.0f;                                   \
                bool conf = (fabsf(dd1) > EPS1) &&                          \
                            (!isedge || (fabsf(d2[c]) > EPS2));             \
                bool hit = isedge ? (d2[c] > 0.0f) : (cc[c] > fthr);        \
                float o  = hit ? 1.0f : 0.0f;                               \
                if (!conf)                                                  \
                    o = aes_exact(reg_, lr0 + r, lc0 + c, bsf, esf, fthr);  \
                ov[c] = o;                                                  \
            }                                                               \
            __builtin_nontemporal_store(ov, (f32x4*)(op + (size_t)r * WW)); \
            if (r < 3) S25 = S25f - h5r[r % 5];                             \
        }                                                                   \
    }

    // ---- in-wave pipeline over 4 sub-tiles: no barriers anywhere ----
    LOADREGS(0)
    WRITELDS()

    #pragma unroll
    for (int t = 0; t < WVT; ++t) {
        if (t < WVT - 1) LOADREGS(t + 1)   // next sub-tile flies under compute
        COMPUTE(t)
        if (t < WVT - 1) WRITELDS()        // vmcnt wait + ds_write (wave-local)
    }

#undef LOADREGS
#undef WRITELDS
#undef LOADROWV
#undef COMPUTE
}

extern "C" void kernel_launch(void* const* d_in, const int* in_sizes, int n_in,
                              void* d_out, int out_size, void* d_ws, size_t ws_size,
                              hipStream_t stream) {
    const float* mask = (const float*)d_in[0];
    const float* bs   = (const float*)d_in[1];
    const float* es   = (const float*)d_in[2];
    const float* ft   = (const float*)d_in[3];
    float* out = (float*)d_out;

    dim3 grid(WW / BW, HH / BH, NB);   // 8 x 16 x 16 = 2048 blocks
    aes_kernel<<<grid, 128, 0, stream>>>(mask, bs, es, ft, out);
}

// Round 16
// 36.754 us; speedup vs baseline: 1.0438x; 1.0438x over previous
//
#include <hip/hip_runtime.h>

#define NB 16
#define HH 1024
#define WW 1024
#define TW 128         // tile width  (output)
#define TH 16          // tile height (output)
#define LC 136         // staged cols: global x in [tile_x-4, tile_x+132)
#define LR 20          // staged rows: global y in [tile_y-2, tile_y+18)
#define N4 (LR * (LC / 4))   // float4 tiles to stage = 680
#define NSTG 3               // ceil(N4 / 256)

#define EPS1 2e-4f     // edge-threshold confidence margin (f32 err bound ~3e-6)
#define EPS2 1e-4f     // final-threshold confidence margin (f32 err bound ~2e-5)

typedef float f32x4 __attribute__((ext_vector_type(4)));
typedef float f32x2 __attribute__((ext_vector_type(2)));

// Cold exact-path: recompute one pixel in f64 from LDS (identical math to the
// R1 kernel that scored absmax 0.0 against the np/f64 reference).
__device__ __noinline__ float aes_exact(const float (*raw)[LC], int lr, int lc,
                                        float bsf, float esf, float fthr)
{
    const double bfd   = (double)bsf / 3.0;
    const double ethrd = 0.5 * (double)esf;
    const double fthrd = (double)fthr;
    const double w25d  = (double)(1.0f / 25.0f);

    double s25 = 0.0, s9 = 0.0;
    for (int dy = 0; dy < 5; ++dy)
        for (int dx = 0; dx < 5; ++dx) {
            double v = (double)raw[lr + dy][lc + dx];
            s25 += v;
            if (dy >= 1 && dy <= 3 && dx >= 1 && dx <= 3) s9 += v;
        }
    double c      = (double)raw[lr + 2][lc + 2];
    double edges  = fabs(9.0 * c - s9);
    double sbase  = s25 * w25d;
    double smooth = c * (1.0 - bfd) + sbase * bfd;
    double result = (edges > ethrd) ? smooth : c;
    return (result > fthrd) ? 1.0f : 0.0f;
}

__global__ __launch_bounds__(256)
void aes_kernel(const float* __restrict__ mask,
                const float* __restrict__ blur_strength,
                const float* __restrict__ edge_sensitivity,
                const float* __restrict__ final_threshold,
                float* __restrict__ out)
{
    __shared__ float raw[2][LR][LC];   // 21,760 B -> 7 blocks/CU, 28 waves/CU

    const int b      = blockIdx.z;
    const int tile_y = blockIdx.y * TH;
    const int tx0    = blockIdx.x * (2 * TW);   // this block: tiles tx0, tx0+TW
    const float* m = mask + (size_t)b * (HH * WW);

    const float bsf    = blur_strength[b];
    const float esf    = edge_sensitivity[b];
    const float fthr   = final_threshold[b];
    const float ethr   = 0.5f * esf;          // exact in f32
    const float bff    = bsf / 3.0f;
    const float onembf = 1.0f - bff;
    const float w25f   = 1.0f / 25.0f;

    // thread -> 4 cols x 2 rows micro-tile
    const int tx  = threadIdx.x & 31;         // 32 col groups * 4 = 128
    const int ty  = threadIdx.x >> 5;         // 8 row groups * 2 = 16
    const int lr0 = ty * 2;
    const int lc0 = 4 * tx + 2;

    f32x4 stg[NSTG];   // in-flight staging registers (static index via unroll)

#define STAGE_LOAD(TILE_X)                                                  \
    {                                                                       \
        _Pragma("unroll")                                                   \
        for (int k = 0; k < NSTG; ++k) {                                    \
            int i = (int)threadIdx.x + k * 256;                             \
            f32x4 v = {0.f, 0.f, 0.f, 0.f};                                 \
            if (i < N4) {                                                   \
                int row = i / (LC / 4);                                     \
                int c4  = i - row * (LC / 4);                               \
                int gy  = tile_y - 2 + row;                                 \
                int gx  = (TILE_X) - 4 + 4 * c4;    /* 16B aligned */       \
                if ((unsigned)gy < (unsigned)HH && (unsigned)gx < (unsigned)WW) \
                    v = *(const f32x4*)(m + (size_t)gy * WW + gx);          \
            }                                                               \
            stg[k] = v;                                                     \
        }                                                                   \
    }

#define STAGE_WRITE(BUF)                                                    \
    {                                                                       \
        _Pragma("unroll")                                                   \
        for (int k = 0; k < NSTG; ++k) {                                    \
            int i = (int)threadIdx.x + k * 256;                             \
            if (i < N4) {                                                   \
                int row = i / (LC / 4);                                     \
                int c4  = i - row * (LC / 4);                               \
                *(f32x4*)&raw[(BUF)][row][4 * c4] = stg[k];                 \
            }                                                               \
        }                                                                   \
    }

    // vectorized row load: h3 = (B+D)+C, h5 = (A+E)+h3  (4 vec-adds total)
#define LOADROWV(RB, ROWIDX, K)                                             \
    {                                                                       \
        const float* rp = &RB[(ROWIDX)][0];                                 \
        f32x2 u0 = *(const f32x2*)(rp + lc0);          /* a0 a1 */          \
        f32x4 u1 = *(const f32x4*)(rp + lc0 + 2);      /* a2..a5 */         \
        f32x2 u2 = *(const f32x2*)(rp + lc0 + 6);      /* a6 a7 */          \
        f32x4 A = {u0.x, u0.y, u1.x, u1.y};                                 \
        f32x4 B = {u0.y, u1.x, u1.y, u1.z};                                 \
        f32x4 D = {u1.y, u1.z, u1.w, u2.x};                                 \
        f32x4 E = {u1.z, u1.w, u2.x, u2.y};                                 \
        f32x4 h3v = (B + D) + u1;                                           \
        h3r[(K)] = h3v;                                                     \
        h5r[(K)] = (A + E) + h3v;                                           \
        ccr[(K)] = u1;                                                      \
    }

    // ---- compute one 128x16 tile from LDS buffer BUF (vectorized math) ----
#define COMPUTE(BUF, TILE_X)                                                \
    {                                                                       \
        const float (*rb)[LC] = raw[(BUF)];                                 \
        f32x4 h5r[5], h3r[5], ccr[5];                                       \
        _Pragma("unroll")                                                   \
        for (int k = 0; k < 4; ++k)                                         \
            LOADROWV(rb, lr0 + k, k)                                        \
        f32x4 S25 = (h5r[0] + h5r[1]) + (h5r[2] + h5r[3]);  /* 4 rows */    \
        float* op = out + (size_t)b * (HH * WW)                             \
                        + (size_t)(tile_y + lr0) * WW + (TILE_X) + 4 * tx;  \
        _Pragma("unroll")                                                   \
        for (int r = 0; r < 2; ++r) {                                       \
            LOADROWV(rb, lr0 + r + 4, (r + 4) % 5)                          \
            const int i1 = (r + 1) % 5, i2 = (r + 2) % 5, i3 = (r + 3) % 5; \
            const int i4 = (r + 4) % 5;                                     \
            f32x4 S25f = S25 + h5r[i4];                                     \
            f32x4 S9   = (h3r[i1] + h3r[i3]) + h3r[i2];                     \
            f32x4 cc   = ccr[i2];                                           \
            f32x4 e    = cc * 9.0f - S9;            /* pk_fma */            \
            f32x4 sb   = S25f * w25f;                                       \
            f32x4 sm   = cc * onembf + sb * bff;    /* pk_mul+pk_fma */     \
            f32x4 d2   = sm - fthr;                                         \
            f32x4 ov;                                                       \
            _Pragma("unroll")                                               \
            for (int c = 0; c < 4; ++c) {                                   \
                float ec  = fabsf(e[c]);            /* edges */             \
                float dd1 = ec - ethr;                                      \
                bool isedge = dd1 > 0.0f;                                   \
                bool conf = (fabsf(dd1) > EPS1) &&                          \
                            (!isedge || (fabsf(d2[c]) > EPS2));             \
                bool hit = isedge ? (d2[c] > 0.0f) : (cc[c] > fthr);        \
                float o  = hit ? 1.0f : 0.0f;                               \
                if (!conf)                                                  \
                    o = aes_exact(rb, lr0 + r, lc0 + c, bsf, esf, fthr);    \
                ov[c] = o;                                                  \
            }                                                               \
            __builtin_nontemporal_store(ov, (f32x4*)(op + (size_t)r * WW)); \
            if (r < 1) S25 = S25f - h5r[r % 5];     /* row leaves window */ \
        }                                                                   \
    }

    // ---------------- pipeline: 2 tiles, double-buffered LDS --------------
    STAGE_LOAD(tx0)          // tile 0 -> regs
    STAGE_WRITE(0)           // regs -> LDS[0]   (vmcnt wait auto-inserted)
    __syncthreads();

    STAGE_LOAD(tx0 + TW)     // tile 1 loads fly under tile 0 compute
    COMPUTE(0, tx0)
    STAGE_WRITE(1)           // wait tile-1 loads, write LDS[1]
    __syncthreads();

    COMPUTE(1, tx0 + TW)

#undef STAGE_LOAD
#undef STAGE_WRITE
#undef LOADROWV
#undef COMPUTE
}

extern "C" void kernel_launch(void* const* d_in, const int* in_sizes, int n_in,
                              void* d_out, int out_size, void* d_ws, size_t ws_size,
                              hipStream_t stream) {
    const float* mask = (const float*)d_in[0];
    const float* bs   = (const float*)d_in[1];
    const float* es   = (const float*)d_in[2];
    const float* ft   = (const float*)d_in[3];
    float* out = (float*)d_out;

    dim3 grid(WW / (2 * TW), HH / TH, NB);   // 4 x 64 x 16 = 4096 blocks
    aes_kernel<<<grid, 256, 0, stream>>>(mask, bs, es, ft, out);
}

// Round 17
// 34.435 us; speedup vs baseline: 1.1141x; 1.0674x over previous
//
#include <hip/hip_runtime.h>

#define NB 16
#define HH 1024
#define WW 1024
#define TW 128         // tile width  (output)
#define TH 32          // tile height (output)
#define LC 136         // staged cols: global x in [tile_x-4, tile_x+132)
#define LR 36          // staged rows: global y in [tile_y-2, tile_y+34)
#define N4 (LR * (LC / 4))   // float4 tiles to stage = 1224
#define NSTG 5               // ceil(N4 / 256)

#define EPS1 2e-4f     // edge-threshold confidence margin (f32 err bound ~3e-6)
#define EPS2 1e-4f     // final-threshold confidence margin (f32 err bound ~2e-5)

typedef float f32x4 __attribute__((ext_vector_type(4)));
typedef float f32x2 __attribute__((ext_vector_type(2)));

// Cold exact-path: recompute one pixel in f64 from LDS (identical math to the
// R1 kernel that scored absmax 0.0 against the np/f64 reference).
__device__ __noinline__ float aes_exact(const float (*raw)[LC], int lr, int lc,
                                        float bsf, float esf, float fthr)
{
    const double bfd   = (double)bsf / 3.0;
    const double ethrd = 0.5 * (double)esf;
    const double fthrd = (double)fthr;
    const double w25d  = (double)(1.0f / 25.0f);

    double s25 = 0.0, s9 = 0.0;
    for (int dy = 0; dy < 5; ++dy)
        for (int dx = 0; dx < 5; ++dx) {
            double v = (double)raw[lr + dy][lc + dx];
            s25 += v;
            if (dy >= 1 && dy <= 3 && dx >= 1 && dx <= 3) s9 += v;
        }
    double c      = (double)raw[lr + 2][lc + 2];
    double edges  = fabs(9.0 * c - s9);
    double sbase  = s25 * w25d;
    double smooth = c * (1.0 - bfd) + sbase * bfd;
    double result = (edges > ethrd) ? smooth : c;
    return (result > fthrd) ? 1.0f : 0.0f;
}

__global__ __launch_bounds__(256, 4)
void aes_kernel(const float* __restrict__ mask,
                const float* __restrict__ blur_strength,
                const float* __restrict__ edge_sensitivity,
                const float* __restrict__ final_threshold,
                float* __restrict__ out)
{
    __shared__ float raw[2][LR][LC];   // 39,168 B -> 4 blocks/CU

    const int b      = blockIdx.z;
    const int tile_y = blockIdx.y * TH;
    const int tx0    = blockIdx.x * (2 * TW);   // this block: tiles tx0, tx0+TW
    const float* m = mask + (size_t)b * (HH * WW);

    const float bsf    = blur_strength[b];
    const float esf    = edge_sensitivity[b];
    const float fthr   = final_threshold[b];
    const float ethr   = 0.5f * esf;          // exact in f32
    const float bff    = bsf / 3.0f;
    const float onembf = 1.0f - bff;
    const float w25f   = 1.0f / 25.0f;

    // thread -> 4 cols x 4 rows micro-tile
    const int tx  = threadIdx.x & 31;
    const int ty  = threadIdx.x >> 5;
    const int lr0 = ty * 4;
    const int lc0 = 4 * tx + 2;

    f32x4 stg[NSTG];   // in-flight staging registers (static index via unroll)

#define STAGE_LOAD(TILE_X)                                                  \
    {                                                                       \
        _Pragma("unroll")                                                   \
        for (int k = 0; k < NSTG; ++k) {                                    \
            int i = (int)threadIdx.x + k * 256;                             \
            f32x4 v = {0.f, 0.f, 0.f, 0.f};                                 \
            if (i < N4) {                                                   \
                int row = i / (LC / 4);                                     \
                int c4  = i - row * (LC / 4);                               \
                int gy  = tile_y - 2 + row;                                 \
                int gx  = (TILE_X) - 4 + 4 * c4;    /* 16B aligned */       \
                if ((unsigned)gy < (unsigned)HH && (unsigned)gx < (unsigned)WW) \
                    v = *(const f32x4*)(m + (size_t)gy * WW + gx);          \
            }                                                               \
            stg[k] = v;                                                     \
        }                                                                   \
    }

#define STAGE_WRITE(BUF)                                                    \
    {                                                                       \
        _Pragma("unroll")                                                   \
        for (int k = 0; k < NSTG; ++k) {                                    \
            int i = (int)threadIdx.x + k * 256;                             \
            if (i < N4) {                                                   \
                int row = i / (LC / 4);                                     \
                int c4  = i - row * (LC / 4);                               \
                *(f32x4*)&raw[(BUF)][row][4 * c4] = stg[k];                 \
            }                                                               \
        }                                                                   \
    }

    // vectorized row load: h3 = (B+D)+C, h5 = (A+E)+h3  (4 vec-adds total)
#define LOADROWV(RB, ROWIDX, K)                                             \
    {                                                                       \
        const float* rp = &RB[(ROWIDX)][0];                                 \
        f32x2 u0 = *(const f32x2*)(rp + lc0);          /* a0 a1 */          \
        f32x4 u1 = *(const f32x4*)(rp + lc0 + 2);      /* a2..a5 */         \
        f32x2 u2 = *(const f32x2*)(rp + lc0 + 6);      /* a6 a7 */          \
        f32x4 A = {u0.x, u0.y, u1.x, u1.y};                                 \
        f32x4 B = {u0.y, u1.x, u1.y, u1.z};                                 \
        f32x4 D = {u1.y, u1.z, u1.w, u2.x};                                 \
        f32x4 E = {u1.z, u1.w, u2.x, u2.y};                                 \
        f32x4 h3v = (B + D) + u1;                                           \
        h3r[(K)] = h3v;                                                     \
        h5r[(K)] = (A + E) + h3v;                                           \
        ccr[(K)] = u1;                                                      \
    }

    // ---- compute one 128x32 tile from LDS buffer BUF (vectorized math) ----
#define COMPUTE(BUF, TILE_X)                                                \
    {                                                                       \
        const float (*rb)[LC] = raw[(BUF)];                                 \
        f32x4 h5r[5], h3r[5], ccr[5];                                       \
        _Pragma("unroll")                                                   \
        for (int k = 0; k < 4; ++k)                                         \
            LOADROWV(rb, lr0 + k, k)                                        \
        f32x4 S25 = (h5r[0] + h5r[1]) + (h5r[2] + h5r[3]);  /* 4 rows */    \
        float* op = out + (size_t)b * (HH * WW)                             \
                        + (size_t)(tile_y + ty * 4) * WW + (TILE_X) + 4 * tx; \
        _Pragma("unroll")                                                   \
        for (int r = 0; r < 4; ++r) {                                       \
            LOADROWV(rb, lr0 + r + 4, (r + 4) % 5)                          \
            const int i1 = (r + 1) % 5, i2 = (r + 2) % 5, i3 = (r + 3) % 5; \
            const int i4 = (r + 4) % 5;                                     \
            f32x4 S25f = S25 + h5r[i4];                                     \
            f32x4 S9   = (h3r[i1] + h3r[i3]) + h3r[i2];                     \
            f32x4 cc   = ccr[i2];                                           \
            f32x4 e    = cc * 9.0f - S9;            /* pk_fma */            \
            f32x4 sb   = S25f * w25f;                                       \
            f32x4 sm   = cc * onembf + sb * bff;    /* pk_mul+pk_fma */     \
            f32x4 d2   = sm - fthr;                                         \
            f32x4 ov;                                                       \
            _Pragma("unroll")                                               \
            for (int c = 0; c < 4; ++c) {                                   \
                float ec  = fabsf(e[c]);            /* edges */             \
                float dd1 = ec - ethr;                                      \
                bool isedge = dd1 > 0.0f;                                   \
                bool conf = (fabsf(dd1) > EPS1) &&                          \
                            (!isedge || (fabsf(d2[c]) > EPS2));             \
                bool hit = isedge ? (d2[c] > 0.0f) : (cc[c] > fthr);        \
                float o  = hit ? 1.0f : 0.0f;                               \
                if (!conf)                                                  \
                    o = aes_exact(rb, lr0 + r, lc0 + c, bsf, esf, fthr);    \
                ov[c] = o;                                                  \
            }                                                               \
            __builtin_nontemporal_store(ov, (f32x4*)(op + (size_t)r * WW)); \
            if (r < 3) S25 = S25f - h5r[r % 5];     /* row leaves window */ \
        }                                                                   \
    }

    // ---------------- pipeline: 2 tiles, double-buffered LDS --------------
    STAGE_LOAD(tx0)          // tile 0 -> regs
    STAGE_WRITE(0)           // regs -> LDS[0]   (vmcnt wait auto-inserted)
    __syncthreads();

    STAGE_LOAD(tx0 + TW)     // tile 1 loads fly under tile 0 compute
    COMPUTE(0, tx0)
    STAGE_WRITE(1)           // wait tile-1 loads, write LDS[1]
    __syncthreads();

    COMPUTE(1, tx0 + TW)

#undef STAGE_LOAD
#undef STAGE_WRITE
#undef LOADROWV
#undef COMPUTE
}

extern "C" void kernel_launch(void* const* d_in, const int* in_sizes, int n_in,
                              void* d_out, int out_size, void* d_ws, size_t ws_size,
                              hipStream_t stream) {
    const float* mask = (const float*)d_in[0];
    const float* bs   = (const float*)d_in[1];
    const float* es   = (const float*)d_in[2];
    const float* ft   = (const float*)d_in[3];
    float* out = (float*)d_out;

    dim3 grid(WW / (2 * TW), HH / TH, NB);   // 4 x 32 x 16 = 2048 blocks
    aes_kernel<<<grid, 256, 0, stream>>>(mask, bs, es, ft, out);
}